// Round 7
// baseline (264.413 us; speedup 1.0000x reference)
//
#include <hip/hip_runtime.h>
#include <math.h>

// Problem constants: x [4, 256, 64, 64] fp32
#define BB   4
#define CC   256
#define NN   4096      // 64*64 spatial
#define GG   8
#define CPG  32        // channels per group
#define EPSV 1e-5f
#define SCALE 0.0625f  // 1/sqrt(256)
#define NSPLIT 4
#define PSTR 40        // ldsP row stride in ushorts (80 B: 16B-aligned rows)

typedef __attribute__((ext_vector_type(8))) short bf16x8;  // 8 bf16 = 4 VGPRs
typedef __attribute__((ext_vector_type(4))) float f32x4;

struct alignas(8) us4 { unsigned short x, y, z, w; };

static __device__ __forceinline__ unsigned short f2bf(float f) {
    union { float f; unsigned int u; } a; a.f = f;
    unsigned int r = a.u + 0x7fffu + ((a.u >> 16) & 1u);   // RNE
    return (unsigned short)(r >> 16);
}
static __device__ __forceinline__ float bf2f(short h) {
    union { unsigned int u; float f; } v;
    v.u = ((unsigned int)(unsigned short)h) << 16;
    return v.f;
}
// async global->LDS, 16B/lane: per-lane gptr, wave-uniform LDS base (+lane*16 by HW)
static __device__ __forceinline__ void async16(const unsigned short* g, unsigned short* l) {
    __builtin_amdgcn_global_load_lds(
        (const __attribute__((address_space(1))) unsigned int*)g,
        (__attribute__((address_space(3))) unsigned int*)l,
        16, 0, 0);
}

// ---------------------------------------------------------------------------
// K0: merged prep: blocks 0..255 = GroupNorm partial stats; 256..511 = weight
// fp32->bf16 conversion (w_qkv 768x256 then w_proj 256x256).
// ---------------------------------------------------------------------------
__global__ __launch_bounds__(256) void prep_kernel(
    const float* __restrict__ x, const float* __restrict__ w_qkv,
    const float* __restrict__ w_proj, float* __restrict__ partials,
    unsigned short* __restrict__ wbf)
{
    const int tid = threadIdx.x;
    if (blockIdx.x >= 256) {
        int idx = ((blockIdx.x - 256)*256 + tid) * 4;     // 0..262140
        float4 v;
        if (idx < 196608) v = *(const float4*)(w_qkv + idx);
        else              v = *(const float4*)(w_proj + (idx - 196608));
        us4 h = { f2bf(v.x), f2bf(v.y), f2bf(v.z), f2bf(v.w) };
        *(us4*)(wbf + idx) = h;
        return;
    }
    const int bg = blockIdx.x >> 3, slice = blockIdx.x & 7;
    const float4* base = (const float4*)(x + (size_t)bg*CPG*NN + slice*16384);
    float s = 0.f, sq = 0.f;
    for (int i = tid; i < 4096; i += 256) {
        float4 v = base[i];
        s  += v.x + v.y + v.z + v.w;
        sq += v.x*v.x + v.y*v.y + v.z*v.z + v.w*v.w;
    }
    __shared__ float ls[256], lq[256];
    ls[tid] = s; lq[tid] = sq;
    __syncthreads();
    for (int off = 128; off > 0; off >>= 1) {
        if (tid < off) { ls[tid] += ls[tid+off]; lq[tid] += lq[tid+off]; }
        __syncthreads();
    }
    if (tid == 0) { partials[blockIdx.x*2] = ls[0]; partials[blockIdx.x*2+1] = lq[0]; }
}

// K1b: finalize stats (32 groups)
__global__ __launch_bounds__(64) void gn_stats2_kernel(const float* __restrict__ partials,
                                                       float* __restrict__ stats) {
    int t = threadIdx.x;
    if (t < 32) {
        float s = 0.f, sq = 0.f;
        for (int i = 0; i < 8; i++) {
            s  += partials[(t*8 + i)*2];
            sq += partials[(t*8 + i)*2 + 1];
        }
        const float cnt = (float)(CPG*NN);
        float mean = s / cnt;
        float var  = sq / cnt - mean*mean;
        stats[t*2]   = mean;
        stats[t*2+1] = rsqrtf(var + EPSV);
    }
}

// ---------------------------------------------------------------------------
// K2: normalize + transpose: x [b][c][n] fp32 -> xnT [(b*4096+n)][256] bf16.
// ---------------------------------------------------------------------------
__global__ __launch_bounds__(256) void norm_t_kernel(
    const float* __restrict__ x, const float* __restrict__ gamma,
    const float* __restrict__ beta, const float* __restrict__ stats,
    unsigned short* __restrict__ xnT)
{
    const int n0 = blockIdx.x * 64;
    const int c0 = blockIdx.y * 64;
    const int b  = blockIdx.z;
    const int tid = threadIdx.x;
    __shared__ unsigned short T[64*68];
    __shared__ float ssc[64], ssh[64];
    if (tid < 64) {
        int c = c0 + tid;
        float mean = stats[(b*GG + (c>>5))*2];
        float rstd = stats[(b*GG + (c>>5))*2 + 1];
        float g = gamma[c], be = beta[c];
        ssc[tid] = rstd*g;
        ssh[tid] = be - mean*rstd*g;
    }
    __syncthreads();
    {
        int cl = tid >> 4, n4 = tid & 15;
        for (int i = 0; i < 4; i++) {
            int c = cl + i*16;
            float4 v = *(const float4*)(x + ((size_t)(b*CC + c0 + c))*NN + n0 + n4*4);
            float sc = ssc[c], sh = ssh[c];
            T[(n4*4+0)*68 + c] = f2bf(v.x*sc + sh);
            T[(n4*4+1)*68 + c] = f2bf(v.y*sc + sh);
            T[(n4*4+2)*68 + c] = f2bf(v.z*sc + sh);
            T[(n4*4+3)*68 + c] = f2bf(v.w*sc + sh);
        }
    }
    __syncthreads();
    {
        int nl = tid >> 3, cs = tid & 7;
        for (int i = 0; i < 2; i++) {
            int n = nl + i*32;
            *(bf16x8*)(xnT + ((size_t)(b*NN + n0 + n))*CC + c0 + cs*8) =
                *(const bf16x8*)&T[n*68 + cs*8];
        }
    }
}

// ---------------------------------------------------------------------------
// K3: QKV MFMA GEMM -> q/k/v in attention frag-chunk layouts (same as R4-R6).
// ---------------------------------------------------------------------------
__global__ __launch_bounds__(256) void qkv_mfma_kernel(
    const unsigned short* __restrict__ xnT, const unsigned short* __restrict__ wbf,
    const float* __restrict__ b_qkv,
    unsigned short* __restrict__ qsw, unsigned short* __restrict__ ksw,
    unsigned short* __restrict__ vsw)
{
    const int tid  = threadIdx.x;
    const int wave = tid >> 6, lane = tid & 63;
    const int lrow = lane & 15, quad = lane >> 4;
    const int R0   = blockIdx.x * 128;
    const int b    = blockIdx.x >> 5;
    const int nb0  = (blockIdx.x & 31) * 128;
    const int oBase = blockIdx.y * 64;
    const int which = oBase >> 8;
    const int o0l   = oBase & 255;
    const bool isV  = (which == 2);
    const int wn = wave >> 1, wo = wave & 1;

    const unsigned short* Abase;
    const unsigned short* Bbase;
    if (!isV) {
        Abase = wbf + ((size_t)(oBase + lrow))*CC + quad*8;
        Bbase = xnT + ((size_t)(R0 + wave*32 + lrow))*CC + quad*8;
    } else {
        Abase = xnT + ((size_t)(R0 + wn*64 + lrow))*CC + quad*8;
        Bbase = wbf + ((size_t)(oBase + wo*32 + lrow))*CC + quad*8;
    }

    f32x4 acc[4][2];
    for (int s = 0; s < 4; s++) for (int t = 0; t < 2; t++)
        acc[s][t] = (f32x4){0.f, 0.f, 0.f, 0.f};

    for (int c0 = 0; c0 < CC; c0 += 32) {
        bf16x8 af[4], bfr[2];
        for (int s = 0; s < 4; s++) af[s]  = *(const bf16x8*)(Abase + s*16*CC + c0);
        for (int t = 0; t < 2; t++) bfr[t] = *(const bf16x8*)(Bbase + t*16*CC + c0);
        for (int s = 0; s < 4; s++)
            for (int t = 0; t < 2; t++)
                acc[s][t] = __builtin_amdgcn_mfma_f32_16x16x32_bf16(af[s], bfr[t], acc[s][t], 0, 0, 0);
    }

    __shared__ unsigned short lds[8192];

    if (!isV) {
        const float sc = (which == 0) ? SCALE : 1.0f;
        for (int s = 0; s < 4; s++) {
            float bias[4];
            for (int r = 0; r < 4; r++) bias[r] = b_qkv[oBase + s*16 + quad*4 + r];
            for (int t = 0; t < 2; t++) {
                us4 h;
                h.x = f2bf((acc[s][t][0] + bias[0]) * sc);
                h.y = f2bf((acc[s][t][1] + bias[1]) * sc);
                h.z = f2bf((acc[s][t][2] + bias[2]) * sc);
                h.w = f2bf((acc[s][t][3] + bias[3]) * sc);
                int chunk = (wave*2 + t)*2 + (s>>1);
                int pos = (((s*2 + (quad>>1)) & 3)*16 + lrow)*8 + (quad&1)*4;
                *(us4*)&lds[chunk*512 + pos] = h;
            }
        }
    } else {
        for (int s = 0; s < 4; s++)
            for (int t = 0; t < 2; t++) {
                int oc = o0l + wo*32 + t*16 + lrow;
                float bias = b_qkv[512 + oc];
                us4 h;
                h.x = f2bf(acc[s][t][0] + bias);
                h.y = f2bf(acc[s][t][1] + bias);
                h.z = f2bf(acc[s][t][2] + bias);
                h.w = f2bf(acc[s][t][3] + bias);
                int chunk = (wn*2 + (s>>1))*4 + wo*2 + t;
                int pos = (((s&1)*2 + (quad>>1))*16 + lrow)*8 + (quad&1)*4;
                *(us4*)&lds[chunk*512 + pos] = h;
            }
    }
    __syncthreads();

    if (!isV) {
        unsigned short* dst = (which == 0) ? qsw : ksw;
        for (int it = 0; it < 4; it++) {
            int f = it*4 + (tid>>6);
            int ng_l = f >> 1, kk_l = f & 1;
            size_t off = ((size_t)(b*256 + (nb0>>4) + ng_l)*8 + (o0l>>5) + kk_l)*512 + lane*8;
            *(bf16x8*)(dst + off) = *(const bf16x8*)&lds[f*512 + lane*8];
        }
    } else {
        for (int it = 0; it < 4; it++) {
            int f = it*4 + (tid>>6);
            int jg_l = f >> 2, ns_l = f & 3;
            size_t off = ((size_t)(b*128 + (nb0>>5) + jg_l)*16 + (o0l>>4) + ns_l)*512 + lane*8;
            *(bf16x8*)(vsw + off) = *(const bf16x8*)&lds[f*512 + lane*8];
        }
    }
}

// ---------------------------------------------------------------------------
// K4: MFMA flash attention (R6 loop) + fp32 ATOMIC epilogue into a single
// combined opart plane (+ atomic lpart). Removes the LDS-bounce epilogue
// and the 4-plane combine downstream.
// ---------------------------------------------------------------------------
__global__ __launch_bounds__(256, 2) void attn_mfma_kernel(
    const unsigned short* __restrict__ qsw, const unsigned short* __restrict__ ksw,
    const unsigned short* __restrict__ vsw,
    float* __restrict__ opart, float* __restrict__ lpart)
{
    const int tid  = threadIdx.x;
    const int wave = tid >> 6, lane = tid & 63;
    const int lrow = lane & 15, quad = lane >> 4;
    const int bx    = blockIdx.x;
    const int split = bx & 3;
    const int ig    = (bx >> 2) & 31;
    const int b     = bx >> 7;
    const int i0w   = ig*128 + wave*32;
    const int koff  = split * (NN / NSPLIT);   // 0,1024,2048,3072
    const int NT    = (NN / NSPLIT) / 32;      // 32 tiles

    __shared__ unsigned short ldsK[8192];          // 16 KB: K tile (single buf)
    __shared__ unsigned short ldsV[2][8192];       // 32 KB: V double buf
    __shared__ unsigned short ldsP[4][32*PSTR];    // 10 KB

    // Q frags (used as B-operand; A/B frag layouts are identical)
    bf16x8 qf[2][8];
    {
        const unsigned short* qb = qsw + ((size_t)b << 20) + (size_t)i0w*256 + lane*8;
        for (int g = 0; g < 2; g++)
            for (int kk = 0; kk < 8; kk++)
                qf[g][kk] = *(const bf16x8*)(qb + g*4096 + kk*512);
    }

    f32x4 o_acc[2][16];
    for (int g = 0; g < 2; g++)
        for (int ns = 0; ns < 16; ns++)
            o_acc[g][ns] = (f32x4){0.f, 0.f, 0.f, 0.f};
    float lsum[2] = {0.f, 0.f};

    // per-lane source pointers (chunk-linear; tile stride 8192 us)
    const unsigned short* kp = ksw + ((size_t)b << 20) + (size_t)koff*256 + wave*2048 + lane*8;
    const unsigned short* vp = vsw + ((size_t)b << 20) + (size_t)koff*256 + wave*2048 + lane*8;

    // preload tile 0 (K + V) via DMA
    for (int t = 0; t < 4; t++) {
        async16(kp + t*512, ldsK + wave*2048 + t*512);
        async16(vp + t*512, ldsV[0] + wave*2048 + t*512);
    }
    __syncthreads();

    for (int jt = 0; jt < NT; jt++) {
        const int cur = jt & 1, nxt = cur ^ 1;

        // async V(t+1) -> other buffer (flies during S-phase)
        if (jt + 1 < NT)
            for (int t = 0; t < 4; t++)
                async16(vp + (size_t)(jt+1)*8192 + t*512, ldsV[nxt] + wave*2048 + t*512);

        // ---- S^T = K Q^T
        f32x4 s[2][2];   // [jg key-group][g query-group]
        for (int jg = 0; jg < 2; jg++)
            for (int g = 0; g < 2; g++)
                s[jg][g] = (f32x4){0.f, 0.f, 0.f, 0.f};
        for (int jg = 0; jg < 2; jg++)
            for (int kk = 0; kk < 8; kk++) {
                bf16x8 kf = *(const bf16x8*)(ldsK + (jg*8 + kk)*512 + lane*8);
                s[jg][0] = __builtin_amdgcn_mfma_f32_16x16x32_bf16(kf, qf[0][kk], s[jg][0], 0, 0, 0);
                s[jg][1] = __builtin_amdgcn_mfma_f32_16x16x32_bf16(kf, qf[1][kk], s[jg][1], 0, 0, 0);
            }

        // ---- p = exp(s); packed b64 P writes; per-lane l partials
        unsigned short* pw = ldsP[wave];
        for (int jg = 0; jg < 2; jg++)
            for (int g = 0; g < 2; g++) {
                float p0 = __expf(s[jg][g][0]);
                float p1 = __expf(s[jg][g][1]);
                float p2 = __expf(s[jg][g][2]);
                float p3 = __expf(s[jg][g][3]);
                lsum[g] += p0 + p1 + p2 + p3;
                us4 h = { f2bf(p0), f2bf(p1), f2bf(p2), f2bf(p3) };
                *(us4*)(pw + (g*16 + lrow)*PSTR + jg*16 + quad*4) = h;
            }

        __syncthreads();   // all waves done with K(t); V(t+1) DMA had S-phase to land

        // async K(t+1) -> single K buffer (flies during PV)
        if (jt + 1 < NT)
            for (int t = 0; t < 4; t++)
                async16(kp + (size_t)(jt+1)*8192 + t*512, ldsK + wave*2048 + t*512);

        // P A-frags: b128 per query-group (rows 80 B apart -> 16B aligned)
        bf16x8 pa[2];
        for (int g = 0; g < 2; g++)
            pa[g] = *(const bf16x8*)(pw + (g*16 + lrow)*PSTR + quad*8);

        // ---- PV from V[cur]
        const unsigned short* lv = ldsV[cur];
        for (int ns = 0; ns < 16; ns++) {
            bf16x8 vf = *(const bf16x8*)(lv + ns*512 + lane*8);
            o_acc[0][ns] = __builtin_amdgcn_mfma_f32_16x16x32_bf16(pa[0], vf, o_acc[0][ns], 0, 0, 0);
            o_acc[1][ns] = __builtin_amdgcn_mfma_f32_16x16x32_bf16(pa[1], vf, o_acc[1][ns], 0, 0, 0);
        }
        __syncthreads();   // K(t+1) DMA had PV to land; V(nxt) visible; P reusable
    }

    // l reduce: queries live on lrow, keys partitioned over quads -> 2 shuffles
    for (int g = 0; g < 2; g++) {
        float v = lsum[g];
        v += __shfl_xor(v, 16);
        v += __shfl_xor(v, 32);
        lsum[g] = v;
    }

    // epilogue: accumulate unnormalized O into the combined fp32 plane.
    // o_acc[g][ns][r]: query = i0w + g*16 + quad*4 + r, channel = ns*16 + lrow
    for (int g = 0; g < 2; g++)
        for (int ns = 0; ns < 16; ns++) {
            float* dst = opart + ((size_t)(b*NN + i0w + g*16 + quad*4))*CC + ns*16 + lrow;
            for (int r = 0; r < 4; r++)
                atomicAdd(dst + (size_t)r*CC, o_acc[g][ns][r]);
        }
    if (quad == 0)
        for (int g = 0; g < 2; g++)
            atomicAdd(lpart + (size_t)b*NN + i0w + g*16 + lrow, lsum[g]);
}

// ---------------------------------------------------------------------------
// K5: proj MFMA v3: A = fp32 opart (combined) * (1/l), B = w_proj bf16.
// grid 512: block = 64 rows x 128 o (2 blocks/CU). Wave = 16 rows x 128 o.
// ---------------------------------------------------------------------------
__global__ __launch_bounds__(256, 2) void proj_mfma_kernel(
    const float* __restrict__ opart, const float* __restrict__ lpart,
    const unsigned short* __restrict__ w2bf, const float* __restrict__ b_proj,
    const float* __restrict__ x, float* __restrict__ out)
{
    const int tid  = threadIdx.x;
    const int wave = tid >> 6, lane = tid & 63;
    const int lrow = lane & 15, quad = lane >> 4;
    const int rt = blockIdx.x >> 1;            // 0..255
    const int oh = blockIdx.x & 1;             // o half
    const int b  = rt >> 6;
    const int n0 = (rt & 63) * 64;
    const int row = n0 + wave*16 + lrow;       // per-lane A row (n within batch)

    const float sinv = 1.0f / lpart[(size_t)b*NN + row];
    const float* Ab = opart + ((size_t)(b*NN + row))*CC + quad*8;

    f32x4 acc[8];
    for (int t = 0; t < 8; t++) acc[t] = (f32x4){0.f, 0.f, 0.f, 0.f};

    for (int c0 = 0; c0 < CC; c0 += 32) {
        float4 a0 = *(const float4*)(Ab + c0);
        float4 a1 = *(const float4*)(Ab + c0 + 4);
        bf16x8 af;
        af[0] = (short)f2bf(a0.x * sinv);
        af[1] = (short)f2bf(a0.y * sinv);
        af[2] = (short)f2bf(a0.z * sinv);
        af[3] = (short)f2bf(a0.w * sinv);
        af[4] = (short)f2bf(a1.x * sinv);
        af[5] = (short)f2bf(a1.y * sinv);
        af[6] = (short)f2bf(a1.z * sinv);
        af[7] = (short)f2bf(a1.w * sinv);
        for (int t = 0; t < 8; t++) {
            bf16x8 bf_ = *(const bf16x8*)(w2bf +
                ((size_t)(oh*128 + t*16 + lrow))*CC + c0 + quad*8);
            acc[t] = __builtin_amdgcn_mfma_f32_16x16x32_bf16(af, bf_, acc[t], 0, 0, 0);
        }
    }

    for (int t = 0; t < 8; t++) {
        int o = oh*128 + t*16 + lrow;
        int n = n0 + wave*16 + quad*4;
        size_t idx = ((size_t)(b*CC + o))*NN + n;
        float bias = b_proj[o];
        float4 xv = *(const float4*)(x + idx);
        float4 ov;
        ov.x = acc[t][0] + bias + xv.x;
        ov.y = acc[t][1] + bias + xv.y;
        ov.z = acc[t][2] + bias + xv.z;
        ov.w = acc[t][3] + bias + xv.w;
        *(float4*)(out + idx) = ov;
    }
}

// ---------------------------------------------------------------------------
extern "C" void kernel_launch(void* const* d_in, const int* in_sizes, int n_in,
                              void* d_out, int out_size, void* d_ws, size_t ws_size,
                              hipStream_t stream) {
    const float* x      = (const float*)d_in[0];
    const float* gamma  = (const float*)d_in[1];
    const float* beta   = (const float*)d_in[2];
    const float* w_qkv  = (const float*)d_in[3];
    const float* b_qkv  = (const float*)d_in[4];
    const float* w_proj = (const float*)d_in[5];
    const float* b_proj = (const float*)d_in[6];
    float* out = (float*)d_out;

    const size_t plane = (size_t)BB * NN * CC;     // 4,194,304 elems
    unsigned short* xnT = (unsigned short*)d_ws;
    unsigned short* qsw = xnT + plane;
    unsigned short* ksw = qsw + plane;
    unsigned short* vsw = ksw + plane;
    unsigned short* wbf = vsw + plane;             // 262144 us
    float* opart    = (float*)(wbf + 262144);      // plane fp32 (combined)
    float* lpart    = opart + plane;               // BB*NN fp32 (combined)
    float* partials = lpart + (size_t)BB*NN;       // 512
    float* stats    = partials + 512;              // 64

    // zero the atomic accumulation buffers (ws is poisoned each launch)
    hipMemsetAsync(opart, 0, (plane + (size_t)BB*NN) * sizeof(float), stream);

    prep_kernel<<<512, 256, 0, stream>>>(x, w_qkv, w_proj, partials, wbf);
    gn_stats2_kernel<<<1, 64, 0, stream>>>(partials, stats);

    dim3 gnt(64, 4, BB);
    norm_t_kernel<<<gnt, 256, 0, stream>>>(x, gamma, beta, stats, xnT);

    dim3 gq(128, 12);
    qkv_mfma_kernel<<<gq, 256, 0, stream>>>(xnT, wbf, b_qkv, qsw, ksw, vsw);

    attn_mfma_kernel<<<BB*32*NSPLIT, 256, 0, stream>>>(qsw, ksw, vsw, opart, lpart);

    proj_mfma_kernel<<<512, 256, 0, stream>>>(opart, lpart, wbf + 196608, b_proj, x, out);
}

// Round 8
// 220.283 us; speedup vs baseline: 1.2003x; 1.2003x over previous
//
#include <hip/hip_runtime.h>
#include <math.h>

// Problem constants: x [4, 256, 64, 64] fp32
#define BB   4
#define CC   256
#define NN   4096      // 64*64 spatial
#define GG   8
#define CPG  32        // channels per group
#define EPSV 1e-5f
#define SCALE 0.0625f  // 1/sqrt(256)
#define NSPLIT 4
#define PSTR 40        // ldsP row stride in ushorts (80 B: 16B-aligned rows)

typedef __attribute__((ext_vector_type(8))) short bf16x8;  // 8 bf16 = 4 VGPRs
typedef __attribute__((ext_vector_type(4))) float f32x4;

struct alignas(8) us4 { unsigned short x, y, z, w; };

static __device__ __forceinline__ unsigned short f2bf(float f) {
    union { float f; unsigned int u; } a; a.f = f;
    unsigned int r = a.u + 0x7fffu + ((a.u >> 16) & 1u);   // RNE
    return (unsigned short)(r >> 16);
}
// async global->LDS, 16B/lane: per-lane gptr, wave-uniform LDS base (+lane*16 by HW)
static __device__ __forceinline__ void async16(const unsigned short* g, unsigned short* l) {
    __builtin_amdgcn_global_load_lds(
        (const __attribute__((address_space(1))) unsigned int*)g,
        (__attribute__((address_space(3))) unsigned int*)l,
        16, 0, 0);
}

// ---------------------------------------------------------------------------
// K0: merged prep: blocks 0..255 = GroupNorm partial stats; 256..511 = weight
// fp32->bf16 conversion (w_qkv 768x256 then w_proj 256x256).
// ---------------------------------------------------------------------------
__global__ __launch_bounds__(256) void prep_kernel(
    const float* __restrict__ x, const float* __restrict__ w_qkv,
    const float* __restrict__ w_proj, float* __restrict__ partials,
    unsigned short* __restrict__ wbf)
{
    const int tid = threadIdx.x;
    if (blockIdx.x >= 256) {
        int idx = ((blockIdx.x - 256)*256 + tid) * 4;     // 0..262140
        float4 v;
        if (idx < 196608) v = *(const float4*)(w_qkv + idx);
        else              v = *(const float4*)(w_proj + (idx - 196608));
        us4 h = { f2bf(v.x), f2bf(v.y), f2bf(v.z), f2bf(v.w) };
        *(us4*)(wbf + idx) = h;
        return;
    }
    const int bg = blockIdx.x >> 3, slice = blockIdx.x & 7;
    const float4* base = (const float4*)(x + (size_t)bg*CPG*NN + slice*16384);
    float s = 0.f, sq = 0.f;
    for (int i = tid; i < 4096; i += 256) {
        float4 v = base[i];
        s  += v.x + v.y + v.z + v.w;
        sq += v.x*v.x + v.y*v.y + v.z*v.z + v.w*v.w;
    }
    __shared__ float ls[256], lq[256];
    ls[tid] = s; lq[tid] = sq;
    __syncthreads();
    for (int off = 128; off > 0; off >>= 1) {
        if (tid < off) { ls[tid] += ls[tid+off]; lq[tid] += lq[tid+off]; }
        __syncthreads();
    }
    if (tid == 0) { partials[blockIdx.x*2] = ls[0]; partials[blockIdx.x*2+1] = lq[0]; }
}

// ---------------------------------------------------------------------------
// K2: normalize + transpose: x [b][c][n] fp32 -> xnT [(b*4096+n)][256] bf16.
// Group stats computed inline from partials (gn_stats2 folded in).
// ---------------------------------------------------------------------------
__global__ __launch_bounds__(256) void norm_t_kernel(
    const float* __restrict__ x, const float* __restrict__ gamma,
    const float* __restrict__ beta, const float* __restrict__ partials,
    unsigned short* __restrict__ xnT)
{
    const int n0 = blockIdx.x * 64;
    const int c0 = blockIdx.y * 64;
    const int b  = blockIdx.z;
    const int tid = threadIdx.x;
    __shared__ unsigned short T[64*68];
    __shared__ float ssc[64], ssh[64];
    if (tid < 64) {
        int c = c0 + tid;
        int bg = b*GG + (c >> 5);
        float s = 0.f, sq = 0.f;
        for (int i = 0; i < 8; i++) {
            s  += partials[(bg*8 + i)*2];
            sq += partials[(bg*8 + i)*2 + 1];
        }
        const float cnt = (float)(CPG*NN);
        float mean = s / cnt;
        float var  = sq / cnt - mean*mean;
        float rstd = rsqrtf(var + EPSV);
        float g = gamma[c], be = beta[c];
        ssc[tid] = rstd*g;
        ssh[tid] = be - mean*rstd*g;
    }
    __syncthreads();
    {
        int cl = tid >> 4, n4 = tid & 15;
        for (int i = 0; i < 4; i++) {
            int c = cl + i*16;
            float4 v = *(const float4*)(x + ((size_t)(b*CC + c0 + c))*NN + n0 + n4*4);
            float sc = ssc[c], sh = ssh[c];
            T[(n4*4+0)*68 + c] = f2bf(v.x*sc + sh);
            T[(n4*4+1)*68 + c] = f2bf(v.y*sc + sh);
            T[(n4*4+2)*68 + c] = f2bf(v.z*sc + sh);
            T[(n4*4+3)*68 + c] = f2bf(v.w*sc + sh);
        }
    }
    __syncthreads();
    {
        int nl = tid >> 3, cs = tid & 7;
        for (int i = 0; i < 2; i++) {
            int n = nl + i*32;
            *(bf16x8*)(xnT + ((size_t)(b*NN + n0 + n))*CC + c0 + cs*8) =
                *(const bf16x8*)&T[n*68 + cs*8];
        }
    }
}

// ---------------------------------------------------------------------------
// K3: QKV MFMA GEMM -> q/k/v in attention frag-chunk layouts (same as R4-R6).
// ---------------------------------------------------------------------------
__global__ __launch_bounds__(256) void qkv_mfma_kernel(
    const unsigned short* __restrict__ xnT, const unsigned short* __restrict__ wbf,
    const float* __restrict__ b_qkv,
    unsigned short* __restrict__ qsw, unsigned short* __restrict__ ksw,
    unsigned short* __restrict__ vsw)
{
    const int tid  = threadIdx.x;
    const int wave = tid >> 6, lane = tid & 63;
    const int lrow = lane & 15, quad = lane >> 4;
    const int R0   = blockIdx.x * 128;
    const int b    = blockIdx.x >> 5;
    const int nb0  = (blockIdx.x & 31) * 128;
    const int oBase = blockIdx.y * 64;
    const int which = oBase >> 8;
    const int o0l   = oBase & 255;
    const bool isV  = (which == 2);
    const int wn = wave >> 1, wo = wave & 1;

    const unsigned short* Abase;
    const unsigned short* Bbase;
    if (!isV) {
        Abase = wbf + ((size_t)(oBase + lrow))*CC + quad*8;
        Bbase = xnT + ((size_t)(R0 + wave*32 + lrow))*CC + quad*8;
    } else {
        Abase = xnT + ((size_t)(R0 + wn*64 + lrow))*CC + quad*8;
        Bbase = wbf + ((size_t)(oBase + wo*32 + lrow))*CC + quad*8;
    }

    f32x4 acc[4][2];
    for (int s = 0; s < 4; s++) for (int t = 0; t < 2; t++)
        acc[s][t] = (f32x4){0.f, 0.f, 0.f, 0.f};

    for (int c0 = 0; c0 < CC; c0 += 32) {
        bf16x8 af[4], bfr[2];
        for (int s = 0; s < 4; s++) af[s]  = *(const bf16x8*)(Abase + s*16*CC + c0);
        for (int t = 0; t < 2; t++) bfr[t] = *(const bf16x8*)(Bbase + t*16*CC + c0);
        for (int s = 0; s < 4; s++)
            for (int t = 0; t < 2; t++)
                acc[s][t] = __builtin_amdgcn_mfma_f32_16x16x32_bf16(af[s], bfr[t], acc[s][t], 0, 0, 0);
    }

    __shared__ unsigned short lds[8192];

    if (!isV) {
        const float sc = (which == 0) ? SCALE : 1.0f;
        for (int s = 0; s < 4; s++) {
            float bias[4];
            for (int r = 0; r < 4; r++) bias[r] = b_qkv[oBase + s*16 + quad*4 + r];
            for (int t = 0; t < 2; t++) {
                us4 h;
                h.x = f2bf((acc[s][t][0] + bias[0]) * sc);
                h.y = f2bf((acc[s][t][1] + bias[1]) * sc);
                h.z = f2bf((acc[s][t][2] + bias[2]) * sc);
                h.w = f2bf((acc[s][t][3] + bias[3]) * sc);
                int chunk = (wave*2 + t)*2 + (s>>1);
                int pos = (((s*2 + (quad>>1)) & 3)*16 + lrow)*8 + (quad&1)*4;
                *(us4*)&lds[chunk*512 + pos] = h;
            }
        }
    } else {
        for (int s = 0; s < 4; s++)
            for (int t = 0; t < 2; t++) {
                int oc = o0l + wo*32 + t*16 + lrow;
                float bias = b_qkv[512 + oc];
                us4 h;
                h.x = f2bf(acc[s][t][0] + bias);
                h.y = f2bf(acc[s][t][1] + bias);
                h.z = f2bf(acc[s][t][2] + bias);
                h.w = f2bf(acc[s][t][3] + bias);
                int chunk = (wn*2 + (s>>1))*4 + wo*2 + t;
                int pos = (((s&1)*2 + (quad>>1))*16 + lrow)*8 + (quad&1)*4;
                *(us4*)&lds[chunk*512 + pos] = h;
            }
    }
    __syncthreads();

    if (!isV) {
        unsigned short* dst = (which == 0) ? qsw : ksw;
        for (int it = 0; it < 4; it++) {
            int f = it*4 + (tid>>6);
            int ng_l = f >> 1, kk_l = f & 1;
            size_t off = ((size_t)(b*256 + (nb0>>4) + ng_l)*8 + (o0l>>5) + kk_l)*512 + lane*8;
            *(bf16x8*)(dst + off) = *(const bf16x8*)&lds[f*512 + lane*8];
        }
    } else {
        for (int it = 0; it < 4; it++) {
            int f = it*4 + (tid>>6);
            int jg_l = f >> 2, ns_l = f & 3;
            size_t off = ((size_t)(b*128 + (nb0>>5) + jg_l)*16 + (o0l>>4) + ns_l)*512 + lane*8;
            *(bf16x8*)(vsw + off) = *(const bf16x8*)&lds[f*512 + lane*8];
        }
    }
}

// ---------------------------------------------------------------------------
// K4: MFMA flash attention (R6 version, measured 81 us).
// S^T orientation, async DMA staging (V dbuf, K single), fixed-max softmax,
// LDS-bounce epilogue -> bf16 opart planes in proj A-frag chunk layout:
//   plane (split,b): chunk rg*8+kk (512 us); element
//   O[rg*16+m][kk*32+q2*8+e] at pos (q2*16+m)*8+e  == lane-linear for (q2,m).
// ---------------------------------------------------------------------------
__global__ __launch_bounds__(256, 2) void attn_mfma_kernel(
    const unsigned short* __restrict__ qsw, const unsigned short* __restrict__ ksw,
    const unsigned short* __restrict__ vsw,
    unsigned short* __restrict__ opart, float* __restrict__ lpart)
{
    const int tid  = threadIdx.x;
    const int wave = tid >> 6, lane = tid & 63;
    const int lrow = lane & 15, quad = lane >> 4;
    const int bx    = blockIdx.x;
    const int split = bx & 3;
    const int ig    = (bx >> 2) & 31;
    const int b     = bx >> 7;
    const int i0w   = ig*128 + wave*32;
    const int koff  = split * (NN / NSPLIT);   // 0,1024,2048,3072
    const int NT    = (NN / NSPLIT) / 32;      // 32 tiles

    __shared__ unsigned short ldsK[8192];          // 16 KB: K tile (single buf)
    __shared__ unsigned short ldsV[2][8192];       // 32 KB: V double buf
    __shared__ unsigned short ldsP[4][32*PSTR];    // 10 KB

    bf16x8 qf[2][8];
    {
        const unsigned short* qb = qsw + ((size_t)b << 20) + (size_t)i0w*256 + lane*8;
        for (int g = 0; g < 2; g++)
            for (int kk = 0; kk < 8; kk++)
                qf[g][kk] = *(const bf16x8*)(qb + g*4096 + kk*512);
    }

    f32x4 o_acc[2][16];
    for (int g = 0; g < 2; g++)
        for (int ns = 0; ns < 16; ns++)
            o_acc[g][ns] = (f32x4){0.f, 0.f, 0.f, 0.f};
    float lsum[2] = {0.f, 0.f};

    const unsigned short* kp = ksw + ((size_t)b << 20) + (size_t)koff*256 + wave*2048 + lane*8;
    const unsigned short* vp = vsw + ((size_t)b << 20) + (size_t)koff*256 + wave*2048 + lane*8;

    for (int t = 0; t < 4; t++) {
        async16(kp + t*512, ldsK + wave*2048 + t*512);
        async16(vp + t*512, ldsV[0] + wave*2048 + t*512);
    }
    __syncthreads();

    for (int jt = 0; jt < NT; jt++) {
        const int cur = jt & 1, nxt = cur ^ 1;

        if (jt + 1 < NT)
            for (int t = 0; t < 4; t++)
                async16(vp + (size_t)(jt+1)*8192 + t*512, ldsV[nxt] + wave*2048 + t*512);

        // ---- S^T = K Q^T
        f32x4 s[2][2];   // [jg key-group][g query-group]
        for (int jg = 0; jg < 2; jg++)
            for (int g = 0; g < 2; g++)
                s[jg][g] = (f32x4){0.f, 0.f, 0.f, 0.f};
        for (int jg = 0; jg < 2; jg++)
            for (int kk = 0; kk < 8; kk++) {
                bf16x8 kf = *(const bf16x8*)(ldsK + (jg*8 + kk)*512 + lane*8);
                s[jg][0] = __builtin_amdgcn_mfma_f32_16x16x32_bf16(kf, qf[0][kk], s[jg][0], 0, 0, 0);
                s[jg][1] = __builtin_amdgcn_mfma_f32_16x16x32_bf16(kf, qf[1][kk], s[jg][1], 0, 0, 0);
            }

        // ---- p = exp(s); packed b64 P writes; per-lane l partials
        unsigned short* pw = ldsP[wave];
        for (int jg = 0; jg < 2; jg++)
            for (int g = 0; g < 2; g++) {
                float p0 = __expf(s[jg][g][0]);
                float p1 = __expf(s[jg][g][1]);
                float p2 = __expf(s[jg][g][2]);
                float p3 = __expf(s[jg][g][3]);
                lsum[g] += p0 + p1 + p2 + p3;
                us4 h = { f2bf(p0), f2bf(p1), f2bf(p2), f2bf(p3) };
                *(us4*)(pw + (g*16 + lrow)*PSTR + jg*16 + quad*4) = h;
            }

        __syncthreads();

        if (jt + 1 < NT)
            for (int t = 0; t < 4; t++)
                async16(kp + (size_t)(jt+1)*8192 + t*512, ldsK + wave*2048 + t*512);

        bf16x8 pa[2];
        for (int g = 0; g < 2; g++)
            pa[g] = *(const bf16x8*)(pw + (g*16 + lrow)*PSTR + quad*8);

        const unsigned short* lv = ldsV[cur];
        for (int ns = 0; ns < 16; ns++) {
            bf16x8 vf = *(const bf16x8*)(lv + ns*512 + lane*8);
            o_acc[0][ns] = __builtin_amdgcn_mfma_f32_16x16x32_bf16(pa[0], vf, o_acc[0][ns], 0, 0, 0);
            o_acc[1][ns] = __builtin_amdgcn_mfma_f32_16x16x32_bf16(pa[1], vf, o_acc[1][ns], 0, 0, 0);
        }
        __syncthreads();
    }

    for (int g = 0; g < 2; g++) {
        float v = lsum[g];
        v += __shfl_xor(v, 16);
        v += __shfl_xor(v, 32);
        lsum[g] = v;
    }

    // epilogue: bounce O through LDS into frag-chunk layout, store b128.
    unsigned short* reg = &ldsV[0][0] + wave*4096;
    const size_t planeb = ((size_t)(split*BB + b)) << 20;
    for (int g = 0; g < 2; g++) {
        for (int ns = 0; ns < 16; ns++) {
            int kk = ns >> 1;
            int posbase = ((ns & 1)*2 + (lrow >> 3))*128 + (lrow & 7) + quad*32;
            for (int r = 0; r < 4; r++)
                reg[kk*512 + posbase + r*8] = f2bf(o_acc[g][ns][r]);
        }
        unsigned short* dst = opart + planeb + ((size_t)((i0w >> 4) + g))*4096;
        for (int kk = 0; kk < 8; kk++)
            *(bf16x8*)(dst + kk*512 + lane*8) = *(const bf16x8*)(reg + kk*512 + lane*8);
    }
    if (quad == 0)
        for (int g = 0; g < 2; g++)
            lpart[(size_t)(split*BB + b)*NN + i0w + g*16 + lrow] = lsum[g];
}

// ---------------------------------------------------------------------------
// K5: proj MFMA v4: K=1024 GEMM over the 4 unnormalized bf16 split planes.
//   out = diag(1/l) * sum_sp (O_sp @ W^T)  + bias + residual
// -> no per-element combine; 1/l applied to fp32 accumulator post-GEMM.
// grid 512: block = 64 n-rows x 128 o (2 blocks/CU). Wave = 16 rows x 128 o.
// A-frags: lane-linear b128 from opart chunk layout; B-frags: W row-major.
// ---------------------------------------------------------------------------
__global__ __launch_bounds__(256, 2) void proj_mfma_kernel(
    const unsigned short* __restrict__ opart, const float* __restrict__ lpart,
    const unsigned short* __restrict__ w2bf, const float* __restrict__ b_proj,
    const float* __restrict__ x, float* __restrict__ out)
{
    const int tid  = threadIdx.x;
    const int wave = tid >> 6, lane = tid & 63;
    const int lrow = lane & 15, quad = lane >> 4;
    const int rt = blockIdx.x >> 1;            // 0..255
    const int oh = blockIdx.x & 1;             // o half
    const int b  = rt >> 6;
    const int n0 = (rt & 63) * 64;

    const int rg = (n0 >> 4) + wave;           // 16-row group within batch
    const unsigned short* Ab = opart + ((size_t)b << 20) + (size_t)rg*4096 + lane*8;
    const size_t pstride = (size_t)BB << 20;   // split-plane stride (us)

    f32x4 acc[8];
    for (int t = 0; t < 8; t++) acc[t] = (f32x4){0.f, 0.f, 0.f, 0.f};

    for (int kk = 0; kk < 8; kk++) {
        bf16x8 bfr[8];
        for (int t = 0; t < 8; t++)
            bfr[t] = *(const bf16x8*)(w2bf +
                ((size_t)(oh*128 + t*16 + lrow))*CC + kk*32 + quad*8);
        for (int sp = 0; sp < NSPLIT; sp++) {
            bf16x8 af = *(const bf16x8*)(Ab + (size_t)sp*pstride + kk*512);
            for (int t = 0; t < 8; t++)
                acc[t] = __builtin_amdgcn_mfma_f32_16x16x32_bf16(af, bfr[t], acc[t], 0, 0, 0);
        }
    }

    // 1/l for this lane's 4 D-rows (n = n0 + wave*16 + quad*4 + r)
    float sinv[4];
    for (int r = 0; r < 4; r++) {
        int n = n0 + wave*16 + quad*4 + r;
        float l = 0.f;
        for (int sp = 0; sp < NSPLIT; sp++)
            l += lpart[(size_t)(sp*BB + b)*NN + n];
        sinv[r] = 1.0f / l;
    }

    for (int t = 0; t < 8; t++) {
        int o = oh*128 + t*16 + lrow;
        int n = n0 + wave*16 + quad*4;
        size_t idx = ((size_t)(b*CC + o))*NN + n;
        float bias = b_proj[o];
        float4 xv = *(const float4*)(x + idx);
        float4 ov;
        ov.x = acc[t][0]*sinv[0] + bias + xv.x;
        ov.y = acc[t][1]*sinv[1] + bias + xv.y;
        ov.z = acc[t][2]*sinv[2] + bias + xv.z;
        ov.w = acc[t][3]*sinv[3] + bias + xv.w;
        *(float4*)(out + idx) = ov;
    }
}

// ---------------------------------------------------------------------------
extern "C" void kernel_launch(void* const* d_in, const int* in_sizes, int n_in,
                              void* d_out, int out_size, void* d_ws, size_t ws_size,
                              hipStream_t stream) {
    const float* x      = (const float*)d_in[0];
    const float* gamma  = (const float*)d_in[1];
    const float* beta   = (const float*)d_in[2];
    const float* w_qkv  = (const float*)d_in[3];
    const float* b_qkv  = (const float*)d_in[4];
    const float* w_proj = (const float*)d_in[5];
    const float* b_proj = (const float*)d_in[6];
    float* out = (float*)d_out;

    const size_t plane = (size_t)BB * NN * CC;     // 4,194,304 elems
    unsigned short* xnT = (unsigned short*)d_ws;
    unsigned short* qsw = xnT + plane;
    unsigned short* ksw = qsw + plane;
    unsigned short* vsw = ksw + plane;
    unsigned short* wbf = vsw + plane;             // 262144 us
    unsigned short* opart = wbf + 262144;          // NSPLIT*plane us (bf16)
    float* lpart    = (float*)(opart + (size_t)NSPLIT*plane);  // NSPLIT*BB*NN
    float* partials = lpart + (size_t)NSPLIT*BB*NN;            // 512

    prep_kernel<<<512, 256, 0, stream>>>(x, w_qkv, w_proj, partials, wbf);

    dim3 gnt(64, 4, BB);
    norm_t_kernel<<<gnt, 256, 0, stream>>>(x, gamma, beta, partials, xnT);

    dim3 gq(128, 12);
    qkv_mfma_kernel<<<gq, 256, 0, stream>>>(xnT, wbf, b_qkv, qsw, ksw, vsw);

    attn_mfma_kernel<<<BB*32*NSPLIT, 256, 0, stream>>>(qsw, ksw, vsw, opart, lpart);

    proj_mfma_kernel<<<512, 256, 0, stream>>>(opart, lpart, wbf + 196608, b_proj, x, out);
}